// Round 6
// baseline (374.357 us; speedup 1.0000x reference)
//
#include <hip/hip_runtime.h>
#include <stdint.h>

#define TOK 32768      // B*S
#define H 768
#define NE 8
#define CAP 8192       // max tokens per expert per rank (expected ~4096, 68-sigma margin)
#define BM 256
#define BN 256
#define BK 32

typedef __bf16 bf16x8 __attribute__((ext_vector_type(8)));
typedef float  f32x4  __attribute__((ext_vector_type(4)));

// ws layout (bytes):
//   [0,64)                      counts[16]  (0..7 rank-0, 8..15 rank-1)
//   [256, +TOK*16)              assign[TOK] : int4 (e0, e1, bits(w0), bits(w1))
//   [OFF_L0/W0/L1/W1, NE*CAP*4 each)  per-rank per-expert token lists + weights
//   [OFF_XB, +TOK*H*2)          x in bf16
//   [OFF_WB, +NE*H*H*2)         expert_w in bf16
#define OFF_ASSIGN 256
#define OFF_L0 (OFF_ASSIGN + TOK*16)
#define OFF_W0 (OFF_L0 + NE*CAP*4)
#define OFF_L1 (OFF_W0 + NE*CAP*4)
#define OFF_W1 (OFF_L1 + NE*CAP*4)
#define OFF_XB (OFF_W1 + NE*CAP*4)
#define OFF_WB (OFF_XB + (size_t)TOK*H*2)

__device__ __forceinline__ unsigned short f2bf(float f) {
    uint32_t u = __builtin_bit_cast(uint32_t, f);
    u = (u + 0x7fffu + ((u >> 16) & 1u)) >> 16;   // RNE
    return (unsigned short)u;
}

__device__ __forceinline__ void async_cp16(const void* g, void* l) {
    __builtin_amdgcn_global_load_lds(
        (const __attribute__((address_space(1))) void*)g,
        (__attribute__((address_space(3))) void*)l, 16, 0, 0);
}

// ---------------- fused: router (blocks [0,8192)) + expert_w fp32->bf16 (rest) ----------------
#define RBLK (TOK / 4)          // 8192 router blocks, 4 tokens each
#define CBLK ((NE * H * H / 4 + 255) / 256)   // 4608 convert blocks

__global__ __launch_bounds__(256) void router_convert(
    const float* __restrict__ x, const float* __restrict__ rw, const float* __restrict__ rb,
    unsigned short* __restrict__ xb, int4* __restrict__ assign,
    const float* __restrict__ ew, unsigned short* __restrict__ wbuf)
{
    if (blockIdx.x >= RBLK) {
        // ---- convert_w part ----
        int i = (blockIdx.x - RBLK) * 256 + threadIdx.x;
        int n4 = NE * H * H / 4;
        if (i < n4) {
            float4 v = ((const float4*)ew)[i];
            ushort4 h;
            h.x = f2bf(v.x); h.y = f2bf(v.y); h.z = f2bf(v.z); h.w = f2bf(v.w);
            ((ushort4*)wbuf)[i] = h;
        }
        return;
    }

    // ---- router part: one wave per token ----
    int wid  = threadIdx.x >> 6;
    int lane = threadIdx.x & 63;
    int token = blockIdx.x * 4 + wid;

    const float4* xr  = (const float4*)(x + (size_t)token * H);
    const float4* rw4 = (const float4*)rw;             // [NE][192] float4

    float s[NE];
    #pragma unroll
    for (int e = 0; e < NE; e++) s[e] = 0.f;

    #pragma unroll
    for (int i = 0; i < 3; i++) {
        int p = lane + 64 * i;                         // float4 index 0..191
        float4 xv = xr[p];
        ushort4 xh;
        xh.x = f2bf(xv.x); xh.y = f2bf(xv.y); xh.z = f2bf(xv.z); xh.w = f2bf(xv.w);
        ((ushort4*)(xb + (size_t)token * H))[p] = xh;
        #pragma unroll
        for (int e = 0; e < NE; e++) {
            float4 wv = rw4[e * 192 + p];
            s[e] += xv.x * wv.x + xv.y * wv.y + xv.z * wv.z + xv.w * wv.w;
        }
    }
    #pragma unroll
    for (int e = 0; e < NE; e++) {
        float v = s[e];
        #pragma unroll
        for (int off = 32; off; off >>= 1) v += __shfl_xor(v, off, 64);
        s[e] = v + rb[e];
    }
    if (lane == 0) {
        int e0 = 0;
        #pragma unroll
        for (int e = 1; e < NE; e++) if (s[e] > s[e0]) e0 = e;   // ties -> lowest idx (np)
        int e1 = -1;
        #pragma unroll
        for (int e = 0; e < NE; e++) {
            if (e == e0) continue;
            if (e1 < 0 || s[e] > s[e1]) e1 = e;
        }
        float mx = s[e0];
        float Z = 0.f;
        #pragma unroll
        for (int e = 0; e < NE; e++) Z += __expf(s[e] - mx);
        float p0 = __expf(s[e0] - mx) / Z;
        float p1 = __expf(s[e1] - mx) / Z;
        float inv = 1.f / (p0 + p1 + 1e-9f);
        int4 a;
        a.x = e0; a.y = e1;
        a.z = __float_as_int(p0 * inv);
        a.w = __float_as_int(p1 * inv);
        assign[token] = a;
    }
}

// ---------------- scatter: per-rank per-expert compact lists, 16 global atomics/block ----------------
#define SCAT_T 1024     // tokens per block
__global__ __launch_bounds__(256) void scatter_kernel(
    const int4* __restrict__ assign, int* __restrict__ counts,
    int* __restrict__ l0, float* __restrict__ w0,
    int* __restrict__ l1, float* __restrict__ w1)
{
    __shared__ int lcnt[2 * NE];
    __shared__ int lbase[2 * NE];
    int tid = threadIdx.x;
    if (tid < 2 * NE) lcnt[tid] = 0;
    __syncthreads();

    int4 a[SCAT_T / 256];
    int  r0[SCAT_T / 256], r1[SCAT_T / 256];
    #pragma unroll
    for (int j = 0; j < SCAT_T / 256; j++) {
        int token = blockIdx.x * SCAT_T + j * 256 + tid;
        a[j] = assign[token];
        r0[j] = atomicAdd(&lcnt[a[j].x], 1);
        r1[j] = atomicAdd(&lcnt[NE + a[j].y], 1);
    }
    __syncthreads();
    if (tid < 2 * NE) lbase[tid] = atomicAdd(&counts[tid], lcnt[tid]);
    __syncthreads();

    #pragma unroll
    for (int j = 0; j < SCAT_T / 256; j++) {
        int token = blockIdx.x * SCAT_T + j * 256 + tid;
        int p0 = lbase[a[j].x] + r0[j];
        int p1 = lbase[NE + a[j].y] + r1[j];
        l0[a[j].x * CAP + p0] = token; w0[a[j].x * CAP + p0] = __int_as_float(a[j].z);
        l1[a[j].y * CAP + p1] = token; w1[a[j].y * CAP + p1] = __int_as_float(a[j].w);
    }
}

// ---------------- grouped gather-GEMM: out (=|+=) w * (x[tok] @ W_e^T + b_e) ----------------
// 256x256 tile, 512 threads (8 waves, 2m x 4n, 128x64 out per wave).
// Rationale (round-5 model): GEMM is bound by LOGICAL load traffic into L1s
// (blocks*(BM+BN)*H*2B = 590 MB @ 128^2 = measured 6.1 TB/s delivery ceiling).
// 256^2 halves that to 302 MB. 3-deep prefetch (4 LDS buffers, counted vmcnt(8),
// pinned barriers) covers latency at 1 block/CU. XCD pin: e = bid & 7.
#define PIN() __builtin_amdgcn_sched_barrier(0)
#define NBUF 4
#define BUFB 32768              // bytes per buffer: A 16KB + B 16KB

template <bool ACCUM>
__global__ __launch_bounds__(512, 2) void expert_gemm(
    const unsigned short* __restrict__ xb, const unsigned short* __restrict__ wb,
    const float* __restrict__ eb, const int* __restrict__ counts,
    const int* __restrict__ lists, const float* __restrict__ wlists,
    float* __restrict__ out)
{
    int bid = blockIdx.x;
    int e   = bid & 7;                   // expert -> XCD pin (bid % 8 round-robin)
    int q   = bid >> 3;
    int n0  = (q % 3) * BN;              // n fastest within expert
    int m0  = (q / 3) * BM;
    int cnt = counts[e];
    if (m0 >= cnt) return;

    __shared__ char  lds[NBUF * BUFB];   // 128 KB: per buffer A[256][32] then B[256][32] bf16
    __shared__ int   toks[BM];
    __shared__ float wts[BM];

    int tid = threadIdx.x;
    if (tid < BM) {
        int g = m0 + tid;
        int t = 0; float w = 0.f;
        if (g < cnt) { t = lists[e * CAP + g]; w = wlists[e * CAP + g]; }
        toks[tid] = t; wts[tid] = w;
    }
    __syncthreads();

    int wid = tid >> 6, lane = tid & 63;
    int wm = wid & 1, wn = wid >> 1;     // 2 m-waves x 4 n-waves
    int quad = lane >> 4, r16 = lane & 15;

    // ---- staging addresses (coalesced: 4 lanes = contiguous 64B of one row) ----
    int sr   = lane >> 2;                // row 0..15 within this wave's 16-row group
    int cs   = (lane & 3) * 8;           // k-element offset of this lane's 16B chunk
    int srow = wid * 16 + sr;            // rows 0..127; +128 for the second half

    const unsigned short* gA0 = xb + (size_t)toks[srow]       * H + cs;
    const unsigned short* gA1 = xb + (size_t)toks[128 + srow] * H + cs;
    const unsigned short* gB0 = wb + ((size_t)e * H + n0 + srow)       * H + cs;
    const unsigned short* gB1 = wb + ((size_t)e * H + n0 + 128 + srow) * H + cs;
    char* dA = lds + wid * 1024;             // wave-uniform base; HW adds lane*16
    char* dB = lds + 16384 + wid * 1024;

    f32x4 acc[8][4] = {};

#define STAGE(buf, kel) do { int _bo = (buf) * BUFB;      \
    async_cp16(gA0 + (kel), dA + _bo);                    \
    async_cp16(gA1 + (kel), dA + _bo + 8192);             \
    async_cp16(gB0 + (kel), dB + _bo);                    \
    async_cp16(gB1 + (kel), dB + _bo + 8192); } while (0)

#define COMPUTE(t) do {                                                           \
    const unsigned short* Ac = (const unsigned short*)(lds + ((t) & 3) * BUFB);   \
    const unsigned short* Bc = Ac + 8192;                                         \
    bf16x8 a[8], b[4];                                                            \
    _Pragma("unroll")                                                             \
    for (int mi = 0; mi < 8; mi++)                                                \
        a[mi] = *(const bf16x8*)(Ac + (wm * 128 + mi * 16 + r16) * BK + quad * 8);\
    _Pragma("unroll")                                                             \
    for (int ni = 0; ni < 4; ni++)                                                \
        b[ni] = *(const bf16x8*)(Bc + (wn * 64 + ni * 16 + r16) * BK + quad * 8); \
    _Pragma("unroll")                                                             \
    for (int mi = 0; mi < 8; mi++)                                                \
        _Pragma("unroll")                                                         \
        for (int ni = 0; ni < 4; ni++)                                            \
            acc[mi][ni] = __builtin_amdgcn_mfma_f32_16x16x32_bf16(                \
                a[mi], b[ni], acc[mi][ni], 0, 0, 0);                              \
} while (0)

// pinned barrier: nothing may be scheduled across the wait or the barrier
#define BOUNDARY(N) do {                                      \
    asm volatile("s_waitcnt vmcnt(" #N ")" ::: "memory");     \
    PIN();                                                    \
    __builtin_amdgcn_s_barrier();                             \
    PIN();                                                    \
    asm volatile("" ::: "memory");                            \
} while (0)

    constexpr int NT = H / BK;       // 24 K-tiles
    STAGE(0, 0);
    STAGE(1, BK);
    STAGE(2, 2 * BK);
    BOUNDARY(0);                     // order-robust prologue drain (tiles 0..2 resident)

    for (int t = 0; t < NT - 3; t++) {
        STAGE((t + 3) & 3, (t + 3) * BK);
        COMPUTE(t);
        // drain tile t+1; tiles t+2, t+3 (8 loads) stay in flight across the barrier
        BOUNDARY(8);
    }
    COMPUTE(NT - 3);
    BOUNDARY(4);                     // drain tile NT-2
    COMPUTE(NT - 2);
    BOUNDARY(0);                     // drain tile NT-1
    COMPUTE(NT - 1);
#undef STAGE
#undef COMPUTE
#undef BOUNDARY

    float bias[4];
    #pragma unroll
    for (int ni = 0; ni < 4; ni++)
        bias[ni] = eb[e * H + n0 + wn * 64 + ni * 16 + r16];

    #pragma unroll
    for (int mi = 0; mi < 8; mi++) {
        int rowb = wm * 128 + mi * 16 + quad * 4;
        #pragma unroll
        for (int r = 0; r < 4; r++) {
            int row = rowb + r;
            if (m0 + row < cnt) {                       // mask tail rows (no zero-clobber)
                float w = wts[row];
                float* orow = out + (size_t)toks[row] * H + n0 + wn * 64;
                #pragma unroll
                for (int ni = 0; ni < 4; ni++) {
                    float v = (acc[mi][ni][r] + bias[ni]) * w;
                    if (ACCUM) v += orow[ni * 16 + r16];   // rows unique within dispatch
                    orow[ni * 16 + r16] = v;
                }
            }
        }
    }
}

extern "C" void kernel_launch(void* const* d_in, const int* in_sizes, int n_in,
                              void* d_out, int out_size, void* d_ws, size_t ws_size,
                              hipStream_t stream) {
    const float* x   = (const float*)d_in[0];
    const float* rw  = (const float*)d_in[1];
    const float* rb  = (const float*)d_in[2];
    const float* ew  = (const float*)d_in[3];
    const float* ebv = (const float*)d_in[4];
    float* out = (float*)d_out;

    char* ws = (char*)d_ws;
    int*   counts = (int*)ws;
    int4*  assign = (int4*)(ws + OFF_ASSIGN);
    int*   l0     = (int*)(ws + OFF_L0);
    float* w0     = (float*)(ws + OFF_W0);
    int*   l1     = (int*)(ws + OFF_L1);
    float* w1     = (float*)(ws + OFF_W1);
    unsigned short* xb = (unsigned short*)(ws + OFF_XB);
    unsigned short* wb = (unsigned short*)(ws + OFF_WB);

    hipMemsetAsync(counts, 0, 64, stream);

    router_convert<<<RBLK + CBLK, 256, 0, stream>>>(x, rw, rb, xb, assign, ew, wb);
    scatter_kernel<<<TOK / SCAT_T, 256, 0, stream>>>(assign, counts, l0, w0, l1, w1);

    int nblk = NE * (H / BN) * (CAP / BM);   // 8 * 3 * 32 = 768, e = bid & 7
    expert_gemm<false><<<nblk, 512, 0, stream>>>(xb, wb, ebv, counts,      l0, w0, out);
    expert_gemm<true ><<<nblk, 512, 0, stream>>>(xb, wb, ebv, counts + NE, l1, w1, out);
}